// Round 4
// baseline (1581.700 us; speedup 1.0000x reference)
//
#include <hip/hip_runtime.h>
#include <cstddef>

// SkipGRU on MI355X (gfx950) — round 4.
// Per step t: [x_t | h] (4096x1024) @ [[W],[U]] (1024x1536) fused with GRU gates.
//
// Round-4 deltas vs round 3 (which measured 24us/step, LDS-BW-bound):
//  - gru_step: block tile 128n x 96c (32 h x 3 gates), grid 32x16=512 (2 blk/CU),
//    waves 2x2, wave = 64n x 48c -> each B frag reused 4x (was 2x). BK=64
//    (2 x 28KB LDS buffers, half the barriers). LDS traffic/chunk-equiv 48->42KB,
//    L2/step 256->224MB.
//  - pack_x: LDS-tiled + XOR-swizzled granules (round-3 version was uncoalesced,
//    1.6 TB/s).
// Layouts:
//  xb[t][nb(64)][kt(16)][g(4)][row(64)][8] bf16 granules (16B).
//  Bt[cc(24)][kt(32)][g(4)][col(64)][8]    (cc = 64 gemm-cols).
//  h ping-pong: same granule layout as xb per nb.

typedef unsigned short u16;
typedef __attribute__((ext_vector_type(8))) short short8;
typedef __attribute__((ext_vector_type(8))) u16 u16x8;
typedef __attribute__((ext_vector_type(4))) float floatx4;

#define MFMA16(a, b, c) __builtin_amdgcn_mfma_f32_16x16x32_bf16((a), (b), (c), 0, 0, 0)

__device__ __forceinline__ u16 f32_to_bf16(float f) {
  union { float f; unsigned int u; } c; c.f = f;
  unsigned int u = c.u + 0x7FFFu + ((c.u >> 16) & 1u);  // RNE
  return (u16)(u >> 16);
}
__device__ __forceinline__ float bf16_to_f32(u16 v) {
  union { unsigned int u; float f; } c; c.u = ((unsigned int)v) << 16;
  return c.f;
}
__device__ __forceinline__ float sigmoidf_(float x) {
  return 1.0f / (1.0f + __expf(-x));
}
__device__ __forceinline__ void gload_lds16(const void* g, void* l) {
  __builtin_amdgcn_global_load_lds(
      (const __attribute__((address_space(1))) unsigned int*)g,
      (__attribute__((address_space(3))) unsigned int*)l, 16, 0, 0);
}

// ---------------------------------------------------------------------------
// pack_x v2: coalesced. Block = one (t, nb): 64 rows x 512 c.
// Phase A: read x rows coalesced (f32x8 / thread), convert, store granules into
// LDS at XOR-swizzled column (ch ^ (row&7)) -> phase-B reads are bank-spread.
// Phase B: write granules [kt][g][row][8] perfectly coalesced.
// ---------------------------------------------------------------------------
__global__ __launch_bounds__(256)
void pack_x(const float* __restrict__ x, u16* __restrict__ xb) {
  __shared__ u16 sm[64 * 512];              // 64KB
  const int t = blockIdx.x >> 6;
  const int nb = blockIdx.x & 63;
  const int tid = threadIdx.x;
#pragma unroll
  for (int it = 0; it < 16; ++it) {
    int idx = it * 256 + tid;
    int row = idx >> 6, ch = idx & 63;      // row 0..63, ch = 8-float chunk
    int xrow = (nb * 2 + (row >> 5)) * 512 + t * 32 + (row & 31);
    const float* src = x + (size_t)xrow * 512 + ch * 8;
    floatx4 va = *(const floatx4*)src;
    floatx4 vb = *(const floatx4*)(src + 4);
    u16x8 pk;
    pk[0] = f32_to_bf16(va[0]); pk[1] = f32_to_bf16(va[1]);
    pk[2] = f32_to_bf16(va[2]); pk[3] = f32_to_bf16(va[3]);
    pk[4] = f32_to_bf16(vb[0]); pk[5] = f32_to_bf16(vb[1]);
    pk[6] = f32_to_bf16(vb[2]); pk[7] = f32_to_bf16(vb[3]);
    *(u16x8*)&sm[row * 512 + (ch ^ (row & 7)) * 8] = pk;
  }
  __syncthreads();
  u16* dst = xb + (size_t)blockIdx.x * 32768;   // blockIdx = t*64+nb = layout order
#pragma unroll
  for (int it = 0; it < 16; ++it) {
    int idx = it * 256 + tid;
    int row = idx & 63, g = (idx >> 6) & 3, kt = idx >> 8;
    int ch = kt * 4 + g;
    u16x8 vv = *(const u16x8*)&sm[row * 512 + (ch ^ (row & 7)) * 8];
    *(u16x8*)(dst + (size_t)idx * 8) = vv;
  }
}

// ---------------------------------------------------------------------------
// pack_Bt: [W;U] -> Bt bf16 [cc(24)][kt(32)][g(4)][col(64)][8]
// ---------------------------------------------------------------------------
__global__ void pack_Bt(const float* __restrict__ W, const float* __restrict__ U,
                        u16* __restrict__ Bt) {
  size_t gid = (size_t)blockIdx.x * 256 + threadIdx.x;   // < 196608
  int col = (int)(gid & 63);
  int g   = (int)((gid >> 6) & 3);
  int kt  = (int)((gid >> 8) & 31);
  int cc  = (int)(gid >> 13);
  int c = cc * 64 + col;
  int k0 = kt * 32 + g * 8;
  u16x8 pk;
#pragma unroll
  for (int j = 0; j < 8; ++j) {
    int k = k0 + j;
    float v = (k < 512) ? W[(size_t)k * 1536 + c] : U[(size_t)(k - 512) * 1536 + c];
    pk[j] = f32_to_bf16(v);
  }
  *(u16x8*)(Bt + gid * 8) = pk;
}

// ---------------------------------------------------------------------------
// gru_step: one GRU timestep. Grid 512: nb2 = idx&31 (128-row pair), hb = idx>>5
// (32 h-cols). 256 thr = 4 waves (wy = nb_sub, wx = 16-h half); wave = 64n x 48c.
// K chunks of 64 (2 kt panels): 8 chunks x@W, 8 chunks h@U.
// LDS: 2 x 28KB: A[2 sub][2 ktl][4 g][64 row][16B] (16KB) + B[3 gate][2 ktl][4 g][32 col][16B] (12KB).
// ---------------------------------------------------------------------------
__global__ __launch_bounds__(256, 2)
void gru_step(const u16* __restrict__ xb, const u16* __restrict__ Bt,
              const float* __restrict__ bias,
              const u16* __restrict__ h_in, u16* __restrict__ h_out,
              float* __restrict__ out, int t, int first, int last) {
  __shared__ alignas(16) char sm[57344];    // 2 x 28672
  const int tid = threadIdx.x;
  const int nb2 = blockIdx.x & 31;          // 0..31 (pair of 64-row nb blocks)
  const int hb  = blockIdx.x >> 5;          // 0..15 (32 h-cols)
  const int w = tid >> 6, lane = tid & 63;
  const int wy = w >> 1, wx = w & 1;
  const int q = lane >> 4, lc = lane & 15;

  const char* xA0 = (const char*)(xb + (size_t)(t * 64 + nb2 * 2) * 32768);
  const char* xA1 = xA0 + 65536;
  const char* hA0 = (const char*)(h_in + (size_t)(nb2 * 2) * 32768);
  const char* hA1 = hA0 + 65536;
  const char* BtB = (const char*)Bt;
  const int colh = (hb & 1) * 512;          // byte offset of 32-col half in panel
  const int cc0 = hb >> 1;                  // z gate col-chunk; r = +8, h = +16

  floatx4 acZ[4] = {{0.f,0.f,0.f,0.f},{0.f,0.f,0.f,0.f},{0.f,0.f,0.f,0.f},{0.f,0.f,0.f,0.f}};
  floatx4 acR[4] = {{0.f,0.f,0.f,0.f},{0.f,0.f,0.f,0.f},{0.f,0.f,0.f,0.f},{0.f,0.f,0.f,0.f}};
  floatx4 acX[4] = {{0.f,0.f,0.f,0.f},{0.f,0.f,0.f,0.f},{0.f,0.f,0.f,0.f},{0.f,0.f,0.f,0.f}};
  floatx4 acH[4] = {{0.f,0.f,0.f,0.f},{0.f,0.f,0.f,0.f},{0.f,0.f,0.f,0.f},{0.f,0.f,0.f,0.f}};

  const int nch = first ? 8 : 16;

  // Stage one K-64 chunk (A 16KB + B 12KB = 28 x 1KB wave-instrs, 7 per wave).
  auto stage = [&](int kc, int bsel) {
    char* lds = sm + bsel * 28672;
#pragma unroll
    for (int j = 0; j < 7; ++j) {
      int i = w * 7 + j;
      if (i < 16) {                          // A: sub(2) x ktl(2) x quarter(4)
        int sub = i >> 3, ktl = (i >> 2) & 1, qq = i & 3;
        const char* base =
            (kc < 8) ? ((sub ? xA1 : xA0) + (size_t)kc * 8192)
                     : ((sub ? hA1 : hA0) + (size_t)(kc - 8) * 8192);
        gload_lds16(base + ktl * 4096 + qq * 1024 + lane * 16,
                    lds + sub * 8192 + ktl * 4096 + qq * 1024);
      } else {                               // B: gate(3) x ktl(2) x ghalf(2)
        int bi = i - 16;
        int gate = bi >> 2, ktl = (bi >> 1) & 1, gh = bi & 1;
        int cc = cc0 + gate * 8;
        int ktg = kc * 2 + ktl;              // global kt 0..31
        gload_lds16(BtB + (size_t)(cc * 32 + ktg) * 4096
                        + (gh * 2 + (lane >> 5)) * 1024 + colh + (lane & 31) * 16,
                    lds + 16384 + gate * 4096 + ktl * 2048 + gh * 1024);
      }
    }
  };

  // Compute one K-64 chunk: 2 k-32 halves x (4 mi x 3 gates) MFMAs.
  auto compute = [&](int bsel, floatx4 (&acT)[4]) {
    const char* lds = sm + bsel * 28672;
#pragma unroll
    for (int jj = 0; jj < 2; ++jj) {
      const char* Ab = lds + wy * 8192 + jj * 4096;
      short8 a0 = *(const short8*)(Ab + (q * 64 +      lc) * 16);
      short8 a1 = *(const short8*)(Ab + (q * 64 + 16 + lc) * 16);
      short8 a2 = *(const short8*)(Ab + (q * 64 + 32 + lc) * 16);
      short8 a3 = *(const short8*)(Ab + (q * 64 + 48 + lc) * 16);
      const char* Bb = lds + 16384 + jj * 2048;
      int co = q * 512 + (wx * 16 + lc) * 16;
      short8 bz = *(const short8*)(Bb + co);
      short8 br = *(const short8*)(Bb + 4096 + co);
      short8 bh = *(const short8*)(Bb + 8192 + co);
      acZ[0] = MFMA16(a0, bz, acZ[0]); acZ[1] = MFMA16(a1, bz, acZ[1]);
      acZ[2] = MFMA16(a2, bz, acZ[2]); acZ[3] = MFMA16(a3, bz, acZ[3]);
      acR[0] = MFMA16(a0, br, acR[0]); acR[1] = MFMA16(a1, br, acR[1]);
      acR[2] = MFMA16(a2, br, acR[2]); acR[3] = MFMA16(a3, br, acR[3]);
      acT[0] = MFMA16(a0, bh, acT[0]); acT[1] = MFMA16(a1, bh, acT[1]);
      acT[2] = MFMA16(a2, bh, acT[2]); acT[3] = MFMA16(a3, bh, acT[3]);
    }
  };

  stage(0, 0);
  __syncthreads();
  for (int kc = 0; kc < nch; ++kc) {
    if (kc + 1 < nch) stage(kc + 1, (kc + 1) & 1);
    if (kc < 8) compute(kc & 1, acX);        // phase 0: x @ W
    else        compute(kc & 1, acH);        // phase 1: h @ U
    __syncthreads();
  }

  // ---- Epilogue. C/D layout: col = lane&15, row = quad*4 + reg ----
  const float* b0 = bias;
  const float* b1 = bias + 1536;
  const int hcl = wx * 16 + lc;              // 0..31
  const int hg = hb * 32 + hcl;              // 0..511
  const float bz = b0[hg] + b1[hg];
  const float brr = b0[512 + hg] + b1[512 + hg];
  const float b0h = b0[1024 + hg];
  const float b1h = b1[1024 + hg];
  const int nbw = nb2 * 2 + wy;              // nb 0..63
  u16* Ct = (u16*)sm;                        // 128 x 34 u16 (buffer 0; last compute used buf 1)
#pragma unroll
  for (int mi = 0; mi < 4; ++mi) {
#pragma unroll
    for (int reg = 0; reg < 4; ++reg) {
      int nl64 = mi * 16 + q * 4 + reg;      // 0..63 within nbw
      float z = sigmoidf_(acZ[mi][reg] + bz);
      float r = sigmoidf_(acR[mi][reg] + brr);
      float hh = acX[mi][reg] + b0h + r * (acH[mi][reg] + b1h);
      hh = fmaxf(hh, 0.0f);
      float hp = 0.0f;
      if (!first)
        hp = bf16_to_f32(h_in[(((size_t)nbw * 16 + hb) * 4 + (hcl >> 3)) * 512
                              + nl64 * 8 + (hcl & 7)]);
      float v = z * hp + (1.0f - z) * hh;
      if (last) out[((size_t)nbw * 64 + nl64) * 512 + hg] = v;
      else      Ct[(wy * 64 + nl64) * 34 + hcl] = f32_to_bf16(v);
    }
  }
  if (!last) {
    __syncthreads();
    // Re-emit h granules: (sub2 x g4 x row64) = 512 granules, 2/thread, coalesced.
#pragma unroll
    for (int i = 0; i < 2; ++i) {
      int e = i * 256 + tid;
      int row = e & 63, g = (e >> 6) & 3, sub = e >> 8;
      u16x8 vv = *(const u16x8*)&Ct[(sub * 64 + row) * 34 + g * 8];
      *(u16x8*)(h_out + ((((size_t)(nb2 * 2 + sub) * 16 + hb) * 4 + g) * 64 + row) * 8) = vv;
    }
  }
}

// ---------------------------------------------------------------------------
extern "C" void kernel_launch(void* const* d_in, const int* in_sizes, int n_in,
                              void* d_out, int out_size, void* d_ws, size_t ws_size,
                              hipStream_t stream) {
  const float* x = (const float*)d_in[0];    // (128,512,512)
  const float* W = (const float*)d_in[1];    // (512,1536)
  const float* U = (const float*)d_in[2];    // (512,1536)
  const float* bias = (const float*)d_in[3]; // (2,1536)
  float* out = (float*)d_out;                // (128,16384)

  u16* xb = (u16*)d_ws;                      // 16*64*32768 u16 = 64 MB
  u16* Bt = xb + (size_t)16 * 64 * 32768;    // 3 MB
  u16* h0 = Bt + (size_t)1536 * 1024;        // 4 MB
  u16* h1 = h0 + (size_t)4096 * 512;         // 4 MB

  pack_x<<<1024, 256, 0, stream>>>(x, xb);
  pack_Bt<<<768, 256, 0, stream>>>(W, U, Bt);

  for (int t = 0; t < 16; ++t) {
    const u16* hin = (t & 1) ? h1 : h0;      // t=0 never reads h
    u16* hout = (t & 1) ? h0 : h1;
    gru_step<<<512, 256, 0, stream>>>(
        xb, Bt, bias, hin, hout, out, t, (t == 0) ? 1 : 0, (t == 15) ? 1 : 0);
  }
}

// Round 5
// 523.572 us; speedup vs baseline: 3.0210x; 3.0210x over previous
//
#include <hip/hip_runtime.h>
#include <cstddef>

// SkipGRU on MI355X (gfx950) — round 5.
// = round 3 structure (64n x 192c tile, BK=32, 2x16KB dbuf, XCD swizzle,
//   known 24us/step) + ONE fix: wave id via readfirstlane so all
//   global_load_lds LDS destinations are provably wave-uniform (round 3/4
//   computed them from a VGPR -> compiler emits a waterfall loop around
//   every global_load_lds; round 4's divergent-looking branch made it worse).
// + round-4's coalesced LDS-tiled pack_x.
//
// Layouts:
//  xb[t][nb(64)][kt(16)][g(4)][row(64)][8] bf16 granules (16B).
//  Bt[cc(24)][kt(32)][g(4)][col(64)][8]    (cc = 64 gemm-cols).
//  h ping-pong: same granule layout as xb per nb.

typedef unsigned short u16;
typedef __attribute__((ext_vector_type(8))) short short8;
typedef __attribute__((ext_vector_type(8))) u16 u16x8;
typedef __attribute__((ext_vector_type(4))) float floatx4;

#define MFMA16(a, b, c) __builtin_amdgcn_mfma_f32_16x16x32_bf16((a), (b), (c), 0, 0, 0)

__device__ __forceinline__ u16 f32_to_bf16(float f) {
  union { float f; unsigned int u; } c; c.f = f;
  unsigned int u = c.u + 0x7FFFu + ((c.u >> 16) & 1u);  // RNE
  return (u16)(u >> 16);
}
__device__ __forceinline__ float bf16_to_f32(u16 v) {
  union { unsigned int u; float f; } c; c.u = ((unsigned int)v) << 16;
  return c.f;
}
__device__ __forceinline__ float sigmoidf_(float x) {
  return 1.0f / (1.0f + __expf(-x));
}
__device__ __forceinline__ void gload_lds16(const void* g, void* l) {
  __builtin_amdgcn_global_load_lds(
      (const __attribute__((address_space(1))) unsigned int*)g,
      (__attribute__((address_space(3))) unsigned int*)l, 16, 0, 0);
}

// ---------------------------------------------------------------------------
// pack_x: coalesced. Block = one (t, nb): 64 rows x 512 c.
// Phase A: read x rows coalesced (f32x8/thread), convert, store granules into
// LDS at XOR-swizzled column; Phase B: write granules [kt][g][row][8] coalesced.
// ---------------------------------------------------------------------------
__global__ __launch_bounds__(256)
void pack_x(const float* __restrict__ x, u16* __restrict__ xb) {
  __shared__ u16 sm[64 * 512];              // 64KB
  const int t = blockIdx.x >> 6;
  const int nb = blockIdx.x & 63;
  const int tid = threadIdx.x;
#pragma unroll
  for (int it = 0; it < 16; ++it) {
    int idx = it * 256 + tid;
    int row = idx >> 6, ch = idx & 63;      // row 0..63, ch = 8-float chunk
    int xrow = (nb * 2 + (row >> 5)) * 512 + t * 32 + (row & 31);
    const float* src = x + (size_t)xrow * 512 + ch * 8;
    floatx4 va = *(const floatx4*)src;
    floatx4 vb = *(const floatx4*)(src + 4);
    u16x8 pk;
    pk[0] = f32_to_bf16(va[0]); pk[1] = f32_to_bf16(va[1]);
    pk[2] = f32_to_bf16(va[2]); pk[3] = f32_to_bf16(va[3]);
    pk[4] = f32_to_bf16(vb[0]); pk[5] = f32_to_bf16(vb[1]);
    pk[6] = f32_to_bf16(vb[2]); pk[7] = f32_to_bf16(vb[3]);
    *(u16x8*)&sm[row * 512 + (ch ^ (row & 7)) * 8] = pk;
  }
  __syncthreads();
  u16* dst = xb + (size_t)blockIdx.x * 32768;   // blockIdx = t*64+nb = layout order
#pragma unroll
  for (int it = 0; it < 16; ++it) {
    int idx = it * 256 + tid;
    int row = idx & 63, g = (idx >> 6) & 3, kt = idx >> 8;
    int ch = kt * 4 + g;
    u16x8 vv = *(const u16x8*)&sm[row * 512 + (ch ^ (row & 7)) * 8];
    *(u16x8*)(dst + (size_t)idx * 8) = vv;
  }
}

// ---------------------------------------------------------------------------
// pack_Bt: [W;U] -> Bt bf16 [cc(24)][kt(32)][g(4)][col(64)][8]
// ---------------------------------------------------------------------------
__global__ void pack_Bt(const float* __restrict__ W, const float* __restrict__ U,
                        u16* __restrict__ Bt) {
  size_t gid = (size_t)blockIdx.x * 256 + threadIdx.x;   // < 196608
  int col = (int)(gid & 63);
  int g   = (int)((gid >> 6) & 3);
  int kt  = (int)((gid >> 8) & 31);
  int cc  = (int)(gid >> 13);
  int c = cc * 64 + col;
  int k0 = kt * 32 + g * 8;
  u16x8 pk;
#pragma unroll
  for (int j = 0; j < 8; ++j) {
    int k = k0 + j;
    float v = (k < 512) ? W[(size_t)k * 1536 + c] : U[(size_t)(k - 512) * 1536 + c];
    pk[j] = f32_to_bf16(v);
  }
  *(u16x8*)(Bt + gid * 8) = pk;
}

// ---------------------------------------------------------------------------
// gru_step: one GRU timestep.
// Grid 512 linear, XCD-swizzled: nb = (idx>>6)*8 + (idx&7), hb = (idx>>3)&7
// (all 8 hb-blocks of an nb land on one XCD; per-XCD set = 1MB A/h + 3MB B).
// Block tile 64n x 192c; 4 waves (wy,wx); wave = 32n x (3 gates x 32 h-cols).
// LDS: 2 x 16KB (A 4KB [g4][row64][16B] + B 3 x 4KB [g4][col64][16B]).
// ---------------------------------------------------------------------------
__global__ __launch_bounds__(256)
void gru_step(const u16* __restrict__ xb, const u16* __restrict__ Bt,
              const float* __restrict__ bias,
              const u16* __restrict__ h_in, u16* __restrict__ h_out,
              float* __restrict__ out, int t, int first, int last) {
  __shared__ alignas(16) char sm[32768];
  const int tid = threadIdx.x;
  const int idx = blockIdx.x;
  const int nb = ((idx >> 6) << 3) | (idx & 7);   // 0..63
  const int hb = (idx >> 3) & 7;                  // 0..7
  // WAVE-UNIFORM wave id: forces SGPR so global_load_lds LDS destinations are
  // provably uniform (no compiler waterfall around each load).
  const int w = __builtin_amdgcn_readfirstlane(tid >> 6);
  const int lane = tid & 63;
  const int wy = w >> 1, wx = w & 1;              // scalar
  const int q = lane >> 4, lc = lane & 15;

  const u16* xbB = xb + (size_t)(t * 64 + nb) * 32768;
  const u16* htB = h_in + (size_t)nb * 32768;
  const int cs0 = hb, cs1 = 8 + hb, cs2 = 16 + hb;   // z / r / h-gate col-chunks

  floatx4 acZ[2][2] = {{{0.f,0.f,0.f,0.f},{0.f,0.f,0.f,0.f}},{{0.f,0.f,0.f,0.f},{0.f,0.f,0.f,0.f}}};
  floatx4 acR[2][2] = {{{0.f,0.f,0.f,0.f},{0.f,0.f,0.f,0.f}},{{0.f,0.f,0.f,0.f},{0.f,0.f,0.f,0.f}}};
  floatx4 acX[2][2] = {{{0.f,0.f,0.f,0.f},{0.f,0.f,0.f,0.f}},{{0.f,0.f,0.f,0.f},{0.f,0.f,0.f,0.f}}};
  floatx4 acH[2][2] = {{{0.f,0.f,0.f,0.f},{0.f,0.f,0.f,0.f}},{{0.f,0.f,0.f,0.f},{0.f,0.f,0.f,0.f}}};

  const int ktall = first ? 16 : 32;
  const int wo = w * 1024;   // SGPR: per-wave byte slot within each 4KB panel

  // Stage K-chunk kt (A 4KB + 3 gate-B 4KB) into buffer bsel. 4 glds16/wave.
  auto stage = [&](int kt, int bsel) {
    char* lds = sm + bsel * 16384;            // bsel scalar -> uniform base
    const char* aS = (const char*)((kt < 16) ? (xbB + (size_t)kt * 2048)
                                             : (htB + (size_t)(kt - 16) * 2048));
    gload_lds16(aS + wo + lane * 16, lds + wo);
    gload_lds16((const char*)(Bt + (size_t)(cs0 * 32 + kt) * 2048) + wo + lane * 16,
                lds + 4096 + wo);
    gload_lds16((const char*)(Bt + (size_t)(cs1 * 32 + kt) * 2048) + wo + lane * 16,
                lds + 8192 + wo);
    gload_lds16((const char*)(Bt + (size_t)(cs2 * 32 + kt) * 2048) + wo + lane * 16,
                lds + 12288 + wo);
  };

  // Compute one K-chunk from buffer bsel; third-gate acc is acX (phase0) / acH.
  auto compute = [&](int bsel, floatx4 (&acT)[2][2]) {
    const char* lds = sm + bsel * 16384;
    short8 a0 = *(const short8*)(lds + (q * 64 + wy * 32 + lc) * 16);
    short8 a1 = *(const short8*)(lds + (q * 64 + wy * 32 + 16 + lc) * 16);
#pragma unroll
    for (int ci = 0; ci < 2; ++ci) {
      int co = (q * 64 + wx * 32 + ci * 16 + lc) * 16;
      short8 bz = *(const short8*)(lds + 4096 + co);
      short8 br = *(const short8*)(lds + 8192 + co);
      short8 bh = *(const short8*)(lds + 12288 + co);
      acZ[0][ci] = MFMA16(a0, bz, acZ[0][ci]);
      acZ[1][ci] = MFMA16(a1, bz, acZ[1][ci]);
      acR[0][ci] = MFMA16(a0, br, acR[0][ci]);
      acR[1][ci] = MFMA16(a1, br, acR[1][ci]);
      acT[0][ci] = MFMA16(a0, bh, acT[0][ci]);
      acT[1][ci] = MFMA16(a1, bh, acT[1][ci]);
    }
  };

  stage(0, 0);
  __syncthreads();
  for (int kt = 0; kt < 16; ++kt) {            // phase 0: x @ W  (3rd gate -> acX)
    if (kt + 1 < ktall) stage(kt + 1, (kt + 1) & 1);
    compute(kt & 1, acX);
    __syncthreads();
  }
  if (!first) {
    for (int kt = 16; kt < 32; ++kt) {         // phase 1: h @ U  (3rd gate -> acH)
      if (kt + 1 < 32) stage(kt + 1, (kt + 1) & 1);
      compute(kt & 1, acH);
      __syncthreads();
    }
  }

  // ---- Epilogue. C/D layout: col = lane&15, row = quad*4 + reg ----
  const float* b0 = bias;
  const float* b1 = bias + 1536;
  u16* Ct = (u16*)sm;    // 64 rows x 72 u16 (9KB); all compute done (final barrier above)
#pragma unroll
  for (int ci = 0; ci < 2; ++ci) {
    const int hcl = wx * 32 + ci * 16 + lc;    // 0..63
    const int hg = hb * 64 + hcl;              // 0..511
    const float bz = b0[hg] + b1[hg];
    const float br = b0[512 + hg] + b1[512 + hg];
    const float b0h = b0[1024 + hg];
    const float b1h = b1[1024 + hg];
    const int ktg = hg >> 5;
    const int gg = (hg >> 3) & 3;
    const size_t hbase = (((size_t)nb * 16 + ktg) * 4 + gg) * 64;
#pragma unroll
    for (int mi = 0; mi < 2; ++mi) {
#pragma unroll
      for (int reg = 0; reg < 4; ++reg) {
        const int nl = wy * 32 + mi * 16 + q * 4 + reg;   // 0..63
        const int n = nb * 64 + nl;
        float z = sigmoidf_(acZ[mi][ci][reg] + bz);
        float r = sigmoidf_(acR[mi][ci][reg] + br);
        float hh = acX[mi][ci][reg] + b0h + r * (acH[mi][ci][reg] + b1h);
        hh = fmaxf(hh, 0.0f);
        float hp = 0.0f;
        if (!first) hp = bf16_to_f32(h_in[(hbase + nl) * 8 + (hg & 7)]);
        float v = z * hp + (1.0f - z) * hh;
        if (last) out[(size_t)n * 512 + hg] = v;
        else      Ct[nl * 72 + hcl] = f32_to_bf16(v);
      }
    }
  }
  if (!last) {
    __syncthreads();
    // Re-emit h in granule layout: 512 granules (row64 x g4 x ktl2), 2/thread.
#pragma unroll
    for (int i = 0; i < 2; ++i) {
      int e = i * 256 + tid;
      int row = e & 63;
      int g = (e >> 6) & 3;
      int ktl = e >> 8;                         // 0..1
      u16x8 vv = *(const u16x8*)(Ct + row * 72 + ktl * 32 + g * 8);
      *(u16x8*)(h_out + ((((size_t)nb * 16 + (hb * 2 + ktl)) * 4 + g) * 64 + row) * 8) = vv;
    }
  }
}

// ---------------------------------------------------------------------------
extern "C" void kernel_launch(void* const* d_in, const int* in_sizes, int n_in,
                              void* d_out, int out_size, void* d_ws, size_t ws_size,
                              hipStream_t stream) {
  const float* x = (const float*)d_in[0];    // (128,512,512)
  const float* W = (const float*)d_in[1];    // (512,1536)
  const float* U = (const float*)d_in[2];    // (512,1536)
  const float* bias = (const float*)d_in[3]; // (2,1536)
  float* out = (float*)d_out;                // (128,16384)

  u16* xb = (u16*)d_ws;                      // 16*64*32768 u16 = 64 MB
  u16* Bt = xb + (size_t)16 * 64 * 32768;    // 3 MB
  u16* h0 = Bt + (size_t)1536 * 1024;        // 4 MB
  u16* h1 = h0 + (size_t)4096 * 512;         // 4 MB

  pack_x<<<1024, 256, 0, stream>>>(x, xb);
  pack_Bt<<<768, 256, 0, stream>>>(W, U, Bt);

  for (int t = 0; t < 16; ++t) {
    const u16* hin = (t & 1) ? h1 : h0;      // t=0 never reads h
    u16* hout = (t & 1) ? h0 : h1;
    gru_step<<<512, 256, 0, stream>>>(
        xb, Bt, bias, hin, hout, out, t, (t == 0) ? 1 : 0, (t == 15) ? 1 : 0);
  }
}